// Round 6
// baseline (1156.492 us; speedup 1.0000x reference)
//
#include <hip/hip_runtime.h>
#include <cstddef>

// ---------------- problem constants ----------------
#define NB 16
#define NC 256
#define NH 32
#define NW 32
#define NK 81

// LDS float offsets (1 block/CU). Stride-36 rows: 9*row = row (mod 8) -> all 8 bank-groups.
#define L_FLT    0        // [256][36]  flt row
#define L_FG     9216     // [256][36]  filter-grad row
#define L_MRES   18432    // [81][36]   mapped residuals (C reuses as sg^2 scratch)
#define L_SMASK  21348    // [81][36]
#define L_FS     24264    // corr staging [32][9][44]=12672; red 4x2916; B [256][44]=11264; pp [128][36]
#define L_CL     36936    // local consts [245]
#define L_ANUM   37184    // [32]
#define L_ALPHA  37216    // [32]
#define L_TOTAL  37248

__device__ __forceinline__ float4 ld4(const float* p) { return *reinterpret_cast<const float4*>(p); }
__device__ __forceinline__ void st4(float* p, float4 v) { *reinterpret_cast<float4*>(p) = v; }

__device__ __forceinline__ void map_by(int bi, int& b, int& y) {
    int xcd = bi & 7, slot = bi >> 3;
    b = xcd * 2 + (slot >> 5);
    y = slot & 31;
}

// Correlation pass: scores(k,x) = sum_c A[c,x]*featpad[c,y+dy,x+dx-4]
// Consumers (tid<576): EXACT r2 compute/order (bitwise-identical results).
// Producers (tid>=576): prefetch chunk k+1 into regs during compute of chunk k,
// store into LDS just before the barrier -> global tail latency hidden.
__device__ __forceinline__ void corr_pass(float* S, const float* __restrict__ feat,
                                          int a_off, int b, int y, int tid,
                                          int lg, int oct, int dyA, bool compA) {
    float* fs = S + L_FS;
    const float4 z4 = make_float4(0.f, 0.f, 0.f, 0.f);
    // zero halo quads (floats 0..3 and 36..39 of each of the 288 [44] rows)
    if (tid < 576) {
        int row = tid >> 1;
        st4(fs + row * 44 + ((tid & 1) ? 36 : 0), z4);
    }
    // zero full rows of out-of-range dy (only near y edges; never overwritten by stores)
    if (y < 4 || y > 27) {
        for (int dyv = 0; dyv < 9; ++dyv) {
            int ryv = y + dyv - 4;
            if (ryv < 0 || ryv >= 32) {
                for (int i = tid; i < 320; i += 1024) {
                    int c = i / 10, q = i - c * 10;
                    st4(fs + c * 396 + dyv * 44 + q * 4, z4);
                }
            }
        }
    }
    // producer element mapping (static per e; chunk adds 32*NH*NW to the global offset)
    const bool prod = tid >= 576;
    const int p = prod ? (tid - 576) : 0;
    bool   pv[6];
    int    plds[6];
    size_t pg[6];
    float4 R[6];
#pragma unroll
    for (int e = 0; e < 6; e++) {
        int idx = p + e * 448;                  // 0..2687; active if <2304
        int cl = idx / 72, rem = idx - cl * 72;
        int ds = rem >> 3, qs = rem & 7, rys = y + ds - 4;
        pv[e]   = prod && (idx < 2304) && (rys >= 0) && (rys < 32);
        plds[e] = cl * 396 + ds * 44 + 4 + qs * 4;
        pg[e]   = ((size_t)(b * NC + cl) * NH + (rys & 31)) * NW + qs * 4;
        if (pv[e]) R[e] = ld4(feat + pg[e]);    // prefetch chunk 0
    }

    float acc[9][8];
#pragma unroll
    for (int dx = 0; dx < 9; dx++)
#pragma unroll
        for (int i = 0; i < 8; i++) acc[dx][i] = 0.f;

#pragma unroll 1
    for (int chunk = 0; chunk < 8; chunk++) {
        // producers: store chunk k (loaded one full window ago), then issue loads k+1
#pragma unroll
        for (int e = 0; e < 6; e++)
            if (pv[e]) st4(fs + plds[e], R[e]);
        if (chunk < 7) {
#pragma unroll
            for (int e = 0; e < 6; e++)
                if (pv[e]) R[e] = ld4(feat + pg[e] + (size_t)(chunk + 1) * 32 * NH * NW);
        }
        __syncthreads();   // staging visible
        if (compA) {
#pragma unroll
            for (int j = 0; j < 2; j++) {
                const int cl = lg * 2 + j;
                const float* wb = fs + cl * 396 + dyA * 44 + oct * 8;
                float4 w0 = ld4(wb), w1 = ld4(wb + 4), w2 = ld4(wb + 8), w3 = ld4(wb + 12);
                float w[16] = {w0.x, w0.y, w0.z, w0.w, w1.x, w1.y, w1.z, w1.w,
                               w2.x, w2.y, w2.z, w2.w, w3.x, w3.y, w3.z, w3.w};
                const float* fb = S + a_off + (chunk * 32 + cl) * 36 + oct * 8;
                float4 f0 = ld4(fb), f1 = ld4(fb + 4);
                float f[8] = {f0.x, f0.y, f0.z, f0.w, f1.x, f1.y, f1.z, f1.w};
#pragma unroll
                for (int dx = 0; dx < 9; dx++)
#pragma unroll
                    for (int i = 0; i < 8; i++)
                        acc[dx][i] = fmaf(f[i], w[i + dx], acc[dx][i]);
            }
        }
        __syncthreads();   // consumers done reading; producers may overwrite next iter
    }
    // 4-buffer, 4-phase cross-group reduce (exact r2 order; producers lg>=16 never match)
#pragma unroll 1
    for (int ph = 0; ph < 4; ph++) {
        if ((lg >> 2) == ph) {
            float* Bf = fs + (lg & 3) * 2916;
#pragma unroll
            for (int dx = 0; dx < 9; dx++) {
                int idx = (dyA * 9 + dx) * 36 + oct * 8;
                if (ph == 0) {
                    st4(Bf + idx,     make_float4(acc[dx][0], acc[dx][1], acc[dx][2], acc[dx][3]));
                    st4(Bf + idx + 4, make_float4(acc[dx][4], acc[dx][5], acc[dx][6], acc[dx][7]));
                } else {
                    float4 t0 = ld4(Bf + idx), t1 = ld4(Bf + idx + 4);
                    t0.x += acc[dx][0]; t0.y += acc[dx][1]; t0.z += acc[dx][2]; t0.w += acc[dx][3];
                    t1.x += acc[dx][4]; t1.y += acc[dx][5]; t1.z += acc[dx][6]; t1.w += acc[dx][7];
                    st4(Bf + idx, t0); st4(Bf + idx + 4, t1);
                }
            }
        }
        __syncthreads();
    }
}

// ---------------- mega kernel: one block = one (b,y) row, all 3 iterations ----------------
// __launch_bounds__(1024, 4): 4 waves/EU target -> VGPR cap 128 (not 64).
// LDS pins 1 block/CU regardless; the r5 default cap of 64 spilled acc[9][8] to scratch
// (WRITE_SIZE 965 MB). Consumer needs ~84-100 VGPR, producer ~50 -> both fit under 128.
__global__ __launch_bounds__(1024, 4) void mega(const float* __restrict__ flt_in,
                                                const float* __restrict__ feat,
                                                float* __restrict__ out,
                                                float* __restrict__ cst_g,
                                                const float* __restrict__ lw,
                                                const float* __restrict__ mw,
                                                const float* __restrict__ sww,
                                                const float* __restrict__ lsl,
                                                const float* __restrict__ fr) {
    __shared__ float S[L_TOTAL];
    int b, y; map_by(blockIdx.x, b, y);
    const int tid = threadIdx.x;

    // A/C consumer mapping (tid<576) — exact r2
    const int lg  = tid / 36;
    const int r36 = tid - lg * 36;
    const int oct = r36 & 3;
    const int dyA = r36 >> 2;
    const int ryA = y + dyA - 4;
    const bool compA = (tid < 576) && (ryA >= 0) && (ryA < 32);
    // B mappings: consumers tid<512 (exact r2), producers tid>=512
    const int octB = tid >> 7;          // 0..3 for consumers
    const int cB   = tid & 127;
    const bool consB = tid < 512;
    const bool prodB = tid >= 512;
    const int pB = prodB ? (tid - 512) : 0;

    // local constants (k_const folded in; per-block LDS-local)
    if (tid < 81) {
        int dyc = tid / 9, dxc = tid - dyc * 9;
        float dist = sqrtf((float)((dyc - 4) * (dyc - 4) + (dxc - 4) * (dxc - 4)));
        float lab = 0.f, mm = 0.f, ss = 0.f;
        for (int d = 0; d < 10; d++) {
            float diff = dist * 2.f - (float)d;
            float bv = (d < 9) ? fmaxf(0.f, 1.f - fabsf(diff))
                               : fminf(fmaxf(1.f + diff, 0.f), 1.f);
            lab += bv * lw[d];
            mm  += bv * mw[d];
            ss  += bv * sww[d];
        }
        S[L_CL + tid]       = lab;
        S[L_CL + 81 + tid]  = 1.f / (1.f + expf(-mm));
        S[L_CL + 162 + tid] = ss;
    } else if (tid == 81) {
        S[L_CL + 243] = expf(lsl[0]);
    } else if (tid == 82) {
        S[L_CL + 244] = fmaxf(fr[0] * fr[0], 1e-10f) * (1.f / 65536.f);
    }
    // stage flt row
    {
        const float* base = flt_in + ((size_t)b * NC * NH + y) * NW;
        for (int i = tid; i < 2048; i += 1024) {
            int c = i >> 3, q = i & 7;
            st4(S + L_FLT + c * 36 + q * 4, ld4(base + c * (NH * NW) + q * 4));
        }
    }
    __syncthreads();
    const float step = S[L_CL + 243];
    const float rw   = S[L_CL + 244];

#pragma unroll 1
    for (int it = 0; it < 3; it++) {
        // ---------- pass A: scores = corr(flt), elementwise -> mres/smask, src loss ----------
        corr_pass(S, feat, L_FLT, b, y, tid, lg, oct, dyA, compA);

        float srcl = 0.f;
        if (tid < 324) {
            const int kk = tid >> 2, o8 = (tid & 3) * 8;
            const int base = kk * 36 + o8;
            const float lab = S[L_CL + kk], m = S[L_CL + 81 + kk], sw = S[L_CL + 162 + kk];
            const float am = 0.5f * (1.f - m), ap = 0.5f * (1.f + m);
#pragma unroll
            for (int h = 0; h < 2; h++) {
                float4 s0 = ld4(S + L_FS + base + h * 4);
                float4 s1 = ld4(S + L_FS + 2916 + base + h * 4);
                float4 s2 = ld4(S + L_FS + 5832 + base + h * 4);
                float4 s3 = ld4(S + L_FS + 8748 + base + h * 4);
                float sv[4] = {s0.x + s1.x + s2.x + s3.x, s0.y + s1.y + s2.y + s3.y,
                               s0.z + s1.z + s2.z + s3.z, s0.w + s1.w + s2.w + s3.w};
                float tr[4], tm[4];
#pragma unroll
                for (int xi = 0; xi < 4; xi++) {
                    float s = sv[xi];
                    float act = am * fabsf(s) + ap * s;
                    float sgn = (s > 0.f ? 1.f : 0.f) - (s < 0.f ? 1.f : 0.f);
                    float msk = am * sgn + ap;
                    float lres = sw * (act - lab);
                    srcl = fmaf(lres, lres, srcl);
                    tr[xi] = msk * sw * lres;
                    tm[xi] = msk;
                }
                st4(S + L_MRES + base + h * 4,  make_float4(tr[0], tr[1], tr[2], tr[3]));
                st4(S + L_SMASK + base + h * 4, make_float4(tm[0], tm[1], tm[2], tm[3]));
            }
        }
#pragma unroll
        for (int off = 32; off > 0; off >>= 1) srcl += __shfl_down(srcl, off, 64);
        if ((tid & 63) == 0) atomicAdd(cst_g + it, srcl);
        __syncthreads();   // mres/smask visible; FS free

        // ---------- pass B: fg = corr_T(mres) + rw*flt; alpha_num; reg loss ----------
        {
            const float4 z4 = make_float4(0.f, 0.f, 0.f, 0.f);
            // zero x-halos of B layout [256][44]: quads 0 and 9 of each row
            for (int i = tid; i < 512; i += 1024) {
                int c = i >> 1, h = i & 1;
                st4(S + L_FS + c * 44 + (h ? 36 : 0), z4);
            }
            float accb[2][8];
#pragma unroll
            for (int j = 0; j < 2; j++)
#pragma unroll
                for (int i = 0; i < 8; i++) accb[j][i] = 0.f;

            const int dy0 = (y < 4) ? (4 - y) : 0;
            const int dyN = (y > 27) ? (36 - y) : 9;
            float4 RB[4];
            if (prodB) {
                int ry0 = y + dy0 - 4;
#pragma unroll
                for (int e = 0; e < 4; e++) {
                    int idx = pB + e * 512, c = idx >> 3, q = idx & 7;
                    RB[e] = ld4(feat + ((size_t)(b * NC + c) * NH + ry0) * NW + q * 4);
                }
            }
#pragma unroll 1
            for (int dy = dy0; dy < dyN; ++dy) {
                __syncthreads();                  // prior consumers done reading FS
                if (prodB) {
#pragma unroll
                    for (int e = 0; e < 4; e++) {
                        int idx = pB + e * 512, c = idx >> 3, q = idx & 7;
                        st4(S + L_FS + c * 44 + 4 + q * 4, RB[e]);
                    }
                    if (dy + 1 < dyN) {           // prefetch next dy during compute window
                        int ry = y + dy - 3;
#pragma unroll
                        for (int e = 0; e < 4; e++) {
                            int idx = pB + e * 512, c = idx >> 3, q = idx & 7;
                            RB[e] = ld4(feat + ((size_t)(b * NC + c) * NH + ry) * NW + q * 4);
                        }
                    }
                }
                __syncthreads();                  // staging visible
                if (consB) {
                    float rr[9][8];
#pragma unroll
                    for (int dx = 0; dx < 9; dx++) {
                        int mi = (dy * 9 + dx) * 36 + octB * 8;   // wave-uniform: broadcast
                        float4 t0 = ld4(S + L_MRES + mi), t1 = ld4(S + L_MRES + mi + 4);
                        rr[dx][0] = t0.x; rr[dx][1] = t0.y; rr[dx][2] = t0.z; rr[dx][3] = t0.w;
                        rr[dx][4] = t1.x; rr[dx][5] = t1.y; rr[dx][6] = t1.z; rr[dx][7] = t1.w;
                    }
#pragma unroll
                    for (int j = 0; j < 2; j++) {
                        const int c = cB + 128 * j;
                        const float* wb = S + L_FS + c * 44 + octB * 8;
                        float4 w0 = ld4(wb), w1 = ld4(wb + 4), w2 = ld4(wb + 8), w3 = ld4(wb + 12);
                        float w[16] = {w0.x, w0.y, w0.z, w0.w, w1.x, w1.y, w1.z, w1.w,
                                       w2.x, w2.y, w2.z, w2.w, w3.x, w3.y, w3.z, w3.w};
#pragma unroll
                        for (int dx = 0; dx < 9; dx++)
#pragma unroll
                            for (int i = 0; i < 8; i++)
                                accb[j][i] = fmaf(rr[dx][i], w[i + dx], accb[j][i]);
                    }
                }
            }
            __syncthreads();   // FS free; fg/anum phase

            float regl = 0.f;
            if (consB) {
                float g[2][8];
#pragma unroll
                for (int j = 0; j < 2; j++) {
                    const int c = cB + 128 * j;
                    const float* fb = S + L_FLT + c * 36 + octB * 8;
                    float4 f0 = ld4(fb), f1 = ld4(fb + 4);
                    float fv[8] = {f0.x, f0.y, f0.z, f0.w, f1.x, f1.y, f1.z, f1.w};
#pragma unroll
                    for (int i = 0; i < 8; i++) {
                        g[j][i] = accb[j][i] + rw * fv[i];
                        regl = fmaf(fv[i], fv[i], regl);
                    }
                    st4(S + L_FG + c * 36 + octB * 8,
                        make_float4(g[j][0], g[j][1], g[j][2], g[j][3]));
                    st4(S + L_FG + c * 36 + octB * 8 + 4,
                        make_float4(g[j][4], g[j][5], g[j][6], g[j][7]));
                }
                float pp[8];
#pragma unroll
                for (int i = 0; i < 8; i++) pp[i] = g[0][i] * g[0][i] + g[1][i] * g[1][i];
                st4(S + L_FS + cB * 36 + octB * 8,     make_float4(pp[0], pp[1], pp[2], pp[3]));
                st4(S + L_FS + cB * 36 + octB * 8 + 4, make_float4(pp[4], pp[5], pp[6], pp[7]));
            }
#pragma unroll
            for (int off = 32; off > 0; off >>= 1) regl += __shfl_down(regl, off, 64);
            if ((tid & 63) == 0) atomicAdd(cst_g + 3 + it, regl);
            __syncthreads();
            if (tid < 32) {
                float s = 0.f;
                for (int c2 = 0; c2 < 128; c2++) s += S[L_FS + c2 * 36 + tid];
                S[L_ANUM + tid] = s;
            }
            __syncthreads();
        }

        // ---------- pass C: sg = corr(fg)*sw*mask; alpha; flt update ----------
        corr_pass(S, feat, L_FG, b, y, tid, lg, oct, dyA, compA);

        if (tid < 324) {
            const int kk = tid >> 2, o8 = (tid & 3) * 8;
            const int base = kk * 36 + o8;
            const float sw = S[L_CL + 162 + kk];
#pragma unroll
            for (int h = 0; h < 2; h++) {
                float4 s0 = ld4(S + L_FS + base + h * 4);
                float4 s1 = ld4(S + L_FS + 2916 + base + h * 4);
                float4 s2 = ld4(S + L_FS + 5832 + base + h * 4);
                float4 s3 = ld4(S + L_FS + 8748 + base + h * 4);
                float4 mk = ld4(S + L_SMASK + base + h * 4);
                float sg0 = sw * mk.x * (s0.x + s1.x + s2.x + s3.x);
                float sg1 = sw * mk.y * (s0.y + s1.y + s2.y + s3.y);
                float sg2 = sw * mk.z * (s0.z + s1.z + s2.z + s3.z);
                float sg3 = sw * mk.w * (s0.w + s1.w + s2.w + s3.w);
                st4(S + L_MRES + base + h * 4,   // mres dead -> sg^2 scratch
                    make_float4(sg0 * sg0, sg1 * sg1, sg2 * sg2, sg3 * sg3));
            }
        }
        __syncthreads();
        if (tid < 32) {
            float den = 0.f;
            for (int k = 0; k < 81; k++) den += S[L_MRES + k * 36 + tid];
            float num = S[L_ANUM + tid];
            float dd = fmaxf(den + rw * num, 1e-8f);
            S[L_ALPHA + tid] = step * num / dd;
        }
        __syncthreads();
        for (int i = tid; i < 2048; i += 1024) {
            int c = i >> 3, q = i & 7;
            float* fp = S + L_FLT + c * 36 + q * 4;
            float4 fl = ld4(fp);
            float4 g = ld4(S + L_FG + c * 36 + q * 4);
            float4 al = ld4(S + L_ALPHA + q * 4);
            fl.x -= al.x * g.x;
            fl.y -= al.y * g.y;
            fl.z -= al.z * g.z;
            fl.w -= al.w * g.w;
            st4(fp, fl);
        }
        __syncthreads();
    }

    // final: write flt row to output
    for (int i = tid; i < 2048; i += 1024) {
        int c = i >> 3, q = i & 7;
        st4(out + ((size_t)(b * NC + c) * NH + y) * NW + q * 4,
            ld4(S + L_FLT + c * 36 + q * 4));
    }
}

// ---------------- tail: write tr, tr_src, tr_reg (separate dispatch, no fences in mega) ----------------
__global__ void k_tail(const float* __restrict__ cst, const float* __restrict__ fr,
                       float* __restrict__ out) {
    int i = threadIdx.x;
    if (i < 3) {
        float rw = fmaxf(fr[0] * fr[0], 1e-10f) * (1.f / 65536.f);
        float src = 0.5f * cst[i] / 16.f;
        float reg = 0.5f * rw * cst[3 + i] / 16.f;
        out[4194304 + i] = src + reg;
        out[4194307 + i] = src;
        out[4194310 + i] = reg;
    }
}

extern "C" void kernel_launch(void* const* d_in, const int* in_sizes, int n_in,
                              void* d_out, int out_size, void* d_ws, size_t ws_size,
                              hipStream_t stream) {
    (void)in_sizes; (void)n_in; (void)out_size; (void)ws_size;
    const float* flt_in = (const float*)d_in[0];
    const float* feat   = (const float*)d_in[1];
    const float* lw     = (const float*)d_in[2];
    const float* mw     = (const float*)d_in[3];
    const float* sww    = (const float*)d_in[4];
    const float* lsl    = (const float*)d_in[5];
    const float* fr     = (const float*)d_in[6];
    float* out = (float*)d_out;
    float* cst = (float*)d_ws;

    hipMemsetAsync(cst, 0, 32, stream);   // src[3], reg[3]
    mega<<<512, 1024, 0, stream>>>(flt_in, feat, out, cst, lw, mw, sww, lsl, fr);
    k_tail<<<1, 64, 0, stream>>>(cst, fr, out);
}

// Round 7
// 1109.255 us; speedup vs baseline: 1.0426x; 1.0426x over previous
//
#include <hip/hip_runtime.h>
#include <cstddef>

// ---------------- problem constants ----------------
#define NB 16
#define NC 256
#define NH 32
#define NW 32
#define NK 81

// LDS float offsets (1 block/CU). Stride-36 rows: 9*row = row (mod 8) -> all 8 bank-groups.
#define L_FLT    0        // [256][36]  flt row
#define L_FG     9216     // [256][36]  filter-grad row
#define L_MRES   18432    // [81][36]   mapped residuals (C reuses as sg^2 scratch)
#define L_SMASK  21348    // [81][36]
#define L_FS     24264    // corr staging [32][9][44]=12672; red 4x2916; B [256][44]=11264; pp [128][36]
#define L_CL     36936    // local consts [245]
#define L_ANUM   37184    // [32]
#define L_ALPHA  37216    // [32]
#define L_TOTAL  37248

__device__ __forceinline__ float4 ld4(const float* p) { return *reinterpret_cast<const float4*>(p); }
__device__ __forceinline__ void st4(float* p, float4 v) { *reinterpret_cast<float4*>(p) = v; }

__device__ __forceinline__ void map_by(int bi, int& b, int& y) {
    int xcd = bi & 7, slot = bi >> 3;
    b = xcd * 2 + (slot >> 5);
    y = slot & 31;
}

// Correlation pass: scores(k,x) = sum_c A[c,x]*featpad[c,y+dy,x+dx-4]
// Consumers (tid<576): EXACT r2 compute/order (bitwise-identical results).
// Producers (tid>=576): prefetch chunk k+1 into regs during compute of chunk k,
// store into LDS just before the barrier -> global tail latency hidden.
__device__ __forceinline__ void corr_pass(float* S, const float* __restrict__ feat,
                                          int a_off, int b, int y, int tid,
                                          int lg, int oct, int dyA, bool compA) {
    float* fs = S + L_FS;
    const float4 z4 = make_float4(0.f, 0.f, 0.f, 0.f);
    // zero halo quads (floats 0..3 and 36..39 of each of the 288 [44] rows)
    if (tid < 576) {
        int row = tid >> 1;
        st4(fs + row * 44 + ((tid & 1) ? 36 : 0), z4);
    }
    // zero full rows of out-of-range dy (only near y edges; never overwritten by stores)
    if (y < 4 || y > 27) {
        for (int dyv = 0; dyv < 9; ++dyv) {
            int ryv = y + dyv - 4;
            if (ryv < 0 || ryv >= 32) {
                for (int i = tid; i < 320; i += 1024) {
                    int c = i / 10, q = i - c * 10;
                    st4(fs + c * 396 + dyv * 44 + q * 4, z4);
                }
            }
        }
    }
    // producer element mapping (static per e; chunk adds 32*NH*NW to the global offset)
    const bool prod = tid >= 576;
    const int p = prod ? (tid - 576) : 0;
    bool   pv[6];
    int    plds[6];
    size_t pg[6];
    float4 R[6];
#pragma unroll
    for (int e = 0; e < 6; e++) {
        int idx = p + e * 448;                  // 0..2687; active if <2304
        int cl = idx / 72, rem = idx - cl * 72;
        int ds = rem >> 3, qs = rem & 7, rys = y + ds - 4;
        pv[e]   = prod && (idx < 2304) && (rys >= 0) && (rys < 32);
        plds[e] = cl * 396 + ds * 44 + 4 + qs * 4;
        pg[e]   = ((size_t)(b * NC + cl) * NH + (rys & 31)) * NW + qs * 4;
        if (pv[e]) R[e] = ld4(feat + pg[e]);    // prefetch chunk 0
    }

    float acc[9][8];
#pragma unroll
    for (int dx = 0; dx < 9; dx++)
#pragma unroll
        for (int i = 0; i < 8; i++) acc[dx][i] = 0.f;

#pragma unroll 1
    for (int chunk = 0; chunk < 8; chunk++) {
        // producers: store chunk k (loaded one full window ago), then issue loads k+1
#pragma unroll
        for (int e = 0; e < 6; e++)
            if (pv[e]) st4(fs + plds[e], R[e]);
        if (chunk < 7) {
#pragma unroll
            for (int e = 0; e < 6; e++)
                if (pv[e]) R[e] = ld4(feat + pg[e] + (size_t)(chunk + 1) * 32 * NH * NW);
        }
        __syncthreads();   // staging visible
        if (compA) {
#pragma unroll
            for (int j = 0; j < 2; j++) {
                const int cl = lg * 2 + j;
                const float* wb = fs + cl * 396 + dyA * 44 + oct * 8;
                float4 w0 = ld4(wb), w1 = ld4(wb + 4), w2 = ld4(wb + 8), w3 = ld4(wb + 12);
                float w[16] = {w0.x, w0.y, w0.z, w0.w, w1.x, w1.y, w1.z, w1.w,
                               w2.x, w2.y, w2.z, w2.w, w3.x, w3.y, w3.z, w3.w};
                const float* fb = S + a_off + (chunk * 32 + cl) * 36 + oct * 8;
                float4 f0 = ld4(fb), f1 = ld4(fb + 4);
                float f[8] = {f0.x, f0.y, f0.z, f0.w, f1.x, f1.y, f1.z, f1.w};
#pragma unroll
                for (int dx = 0; dx < 9; dx++)
#pragma unroll
                    for (int i = 0; i < 8; i++)
                        acc[dx][i] = fmaf(f[i], w[i + dx], acc[dx][i]);
            }
        }
        __syncthreads();   // consumers done reading; producers may overwrite next iter
    }
    // 4-buffer, 4-phase cross-group reduce (exact r2 order; producers lg>=16 never match)
#pragma unroll 1
    for (int ph = 0; ph < 4; ph++) {
        if ((lg >> 2) == ph) {
            float* Bf = fs + (lg & 3) * 2916;
#pragma unroll
            for (int dx = 0; dx < 9; dx++) {
                int idx = (dyA * 9 + dx) * 36 + oct * 8;
                if (ph == 0) {
                    st4(Bf + idx,     make_float4(acc[dx][0], acc[dx][1], acc[dx][2], acc[dx][3]));
                    st4(Bf + idx + 4, make_float4(acc[dx][4], acc[dx][5], acc[dx][6], acc[dx][7]));
                } else {
                    float4 t0 = ld4(Bf + idx), t1 = ld4(Bf + idx + 4);
                    t0.x += acc[dx][0]; t0.y += acc[dx][1]; t0.z += acc[dx][2]; t0.w += acc[dx][3];
                    t1.x += acc[dx][4]; t1.y += acc[dx][5]; t1.z += acc[dx][6]; t1.w += acc[dx][7];
                    st4(Bf + idx, t0); st4(Bf + idx + 4, t1);
                }
            }
        }
        __syncthreads();
    }
}

// ---------------- mega kernel: one block = one (b,y) row, all 3 iterations ----------------
// amdgpu_waves_per_eu(4,4): pin allocator's occupancy TARGET to 4 waves/EU -> 128-VGPR
// budget. launch_bounds' 2nd arg only sets the MIN (a <=128 cap), but the allocator kept
// targeting the default 8 waves/EU -> 64 regs -> acc[9][8] spilled to scratch (r5/r6:
// WRITE_SIZE 965 MB, VGPR=64). LDS (148992 B) pins 1 block/CU = 16 waves = 4/EU anyway.
__global__ __launch_bounds__(1024)
__attribute__((amdgpu_waves_per_eu(4, 4)))
void mega(const float* __restrict__ flt_in,
          const float* __restrict__ feat,
          float* __restrict__ out,
          float* __restrict__ cst_g,
          const float* __restrict__ lw,
          const float* __restrict__ mw,
          const float* __restrict__ sww,
          const float* __restrict__ lsl,
          const float* __restrict__ fr) {
    __shared__ float S[L_TOTAL];
    int b, y; map_by(blockIdx.x, b, y);
    const int tid = threadIdx.x;

    // A/C consumer mapping (tid<576) — exact r2
    const int lg  = tid / 36;
    const int r36 = tid - lg * 36;
    const int oct = r36 & 3;
    const int dyA = r36 >> 2;
    const int ryA = y + dyA - 4;
    const bool compA = (tid < 576) && (ryA >= 0) && (ryA < 32);
    // B mappings: consumers tid<512 (exact r2), producers tid>=512
    const int octB = tid >> 7;          // 0..3 for consumers
    const int cB   = tid & 127;
    const bool consB = tid < 512;
    const bool prodB = tid >= 512;
    const int pB = prodB ? (tid - 512) : 0;

    // local constants (k_const folded in; per-block LDS-local)
    if (tid < 81) {
        int dyc = tid / 9, dxc = tid - dyc * 9;
        float dist = sqrtf((float)((dyc - 4) * (dyc - 4) + (dxc - 4) * (dxc - 4)));
        float lab = 0.f, mm = 0.f, ss = 0.f;
        for (int d = 0; d < 10; d++) {
            float diff = dist * 2.f - (float)d;
            float bv = (d < 9) ? fmaxf(0.f, 1.f - fabsf(diff))
                               : fminf(fmaxf(1.f + diff, 0.f), 1.f);
            lab += bv * lw[d];
            mm  += bv * mw[d];
            ss  += bv * sww[d];
        }
        S[L_CL + tid]       = lab;
        S[L_CL + 81 + tid]  = 1.f / (1.f + expf(-mm));
        S[L_CL + 162 + tid] = ss;
    } else if (tid == 81) {
        S[L_CL + 243] = expf(lsl[0]);
    } else if (tid == 82) {
        S[L_CL + 244] = fmaxf(fr[0] * fr[0], 1e-10f) * (1.f / 65536.f);
    }
    // stage flt row
    {
        const float* base = flt_in + ((size_t)b * NC * NH + y) * NW;
        for (int i = tid; i < 2048; i += 1024) {
            int c = i >> 3, q = i & 7;
            st4(S + L_FLT + c * 36 + q * 4, ld4(base + c * (NH * NW) + q * 4));
        }
    }
    __syncthreads();
    const float step = S[L_CL + 243];
    const float rw   = S[L_CL + 244];

#pragma unroll 1
    for (int it = 0; it < 3; it++) {
        // ---------- pass A: scores = corr(flt), elementwise -> mres/smask, src loss ----------
        corr_pass(S, feat, L_FLT, b, y, tid, lg, oct, dyA, compA);

        float srcl = 0.f;
        if (tid < 324) {
            const int kk = tid >> 2, o8 = (tid & 3) * 8;
            const int base = kk * 36 + o8;
            const float lab = S[L_CL + kk], m = S[L_CL + 81 + kk], sw = S[L_CL + 162 + kk];
            const float am = 0.5f * (1.f - m), ap = 0.5f * (1.f + m);
#pragma unroll
            for (int h = 0; h < 2; h++) {
                float4 s0 = ld4(S + L_FS + base + h * 4);
                float4 s1 = ld4(S + L_FS + 2916 + base + h * 4);
                float4 s2 = ld4(S + L_FS + 5832 + base + h * 4);
                float4 s3 = ld4(S + L_FS + 8748 + base + h * 4);
                float sv[4] = {s0.x + s1.x + s2.x + s3.x, s0.y + s1.y + s2.y + s3.y,
                               s0.z + s1.z + s2.z + s3.z, s0.w + s1.w + s2.w + s3.w};
                float tr[4], tm[4];
#pragma unroll
                for (int xi = 0; xi < 4; xi++) {
                    float s = sv[xi];
                    float act = am * fabsf(s) + ap * s;
                    float sgn = (s > 0.f ? 1.f : 0.f) - (s < 0.f ? 1.f : 0.f);
                    float msk = am * sgn + ap;
                    float lres = sw * (act - lab);
                    srcl = fmaf(lres, lres, srcl);
                    tr[xi] = msk * sw * lres;
                    tm[xi] = msk;
                }
                st4(S + L_MRES + base + h * 4,  make_float4(tr[0], tr[1], tr[2], tr[3]));
                st4(S + L_SMASK + base + h * 4, make_float4(tm[0], tm[1], tm[2], tm[3]));
            }
        }
#pragma unroll
        for (int off = 32; off > 0; off >>= 1) srcl += __shfl_down(srcl, off, 64);
        if ((tid & 63) == 0) atomicAdd(cst_g + it, srcl);
        __syncthreads();   // mres/smask visible; FS free

        // ---------- pass B: fg = corr_T(mres) + rw*flt; alpha_num; reg loss ----------
        {
            const float4 z4 = make_float4(0.f, 0.f, 0.f, 0.f);
            // zero x-halos of B layout [256][44]: quads 0 and 9 of each row
            for (int i = tid; i < 512; i += 1024) {
                int c = i >> 1, h = i & 1;
                st4(S + L_FS + c * 44 + (h ? 36 : 0), z4);
            }
            float accb[2][8];
#pragma unroll
            for (int j = 0; j < 2; j++)
#pragma unroll
                for (int i = 0; i < 8; i++) accb[j][i] = 0.f;

            const int dy0 = (y < 4) ? (4 - y) : 0;
            const int dyN = (y > 27) ? (36 - y) : 9;
            float4 RB[4];
            if (prodB) {
                int ry0 = y + dy0 - 4;
#pragma unroll
                for (int e = 0; e < 4; e++) {
                    int idx = pB + e * 512, c = idx >> 3, q = idx & 7;
                    RB[e] = ld4(feat + ((size_t)(b * NC + c) * NH + ry0) * NW + q * 4);
                }
            }
#pragma unroll 1
            for (int dy = dy0; dy < dyN; ++dy) {
                __syncthreads();                  // prior consumers done reading FS
                if (prodB) {
#pragma unroll
                    for (int e = 0; e < 4; e++) {
                        int idx = pB + e * 512, c = idx >> 3, q = idx & 7;
                        st4(S + L_FS + c * 44 + 4 + q * 4, RB[e]);
                    }
                    if (dy + 1 < dyN) {           // prefetch next dy during compute window
                        int ry = y + dy - 3;
#pragma unroll
                        for (int e = 0; e < 4; e++) {
                            int idx = pB + e * 512, c = idx >> 3, q = idx & 7;
                            RB[e] = ld4(feat + ((size_t)(b * NC + c) * NH + ry) * NW + q * 4);
                        }
                    }
                }
                __syncthreads();                  // staging visible
                if (consB) {
                    float rr[9][8];
#pragma unroll
                    for (int dx = 0; dx < 9; dx++) {
                        int mi = (dy * 9 + dx) * 36 + octB * 8;   // wave-uniform: broadcast
                        float4 t0 = ld4(S + L_MRES + mi), t1 = ld4(S + L_MRES + mi + 4);
                        rr[dx][0] = t0.x; rr[dx][1] = t0.y; rr[dx][2] = t0.z; rr[dx][3] = t0.w;
                        rr[dx][4] = t1.x; rr[dx][5] = t1.y; rr[dx][6] = t1.z; rr[dx][7] = t1.w;
                    }
#pragma unroll
                    for (int j = 0; j < 2; j++) {
                        const int c = cB + 128 * j;
                        const float* wb = S + L_FS + c * 44 + octB * 8;
                        float4 w0 = ld4(wb), w1 = ld4(wb + 4), w2 = ld4(wb + 8), w3 = ld4(wb + 12);
                        float w[16] = {w0.x, w0.y, w0.z, w0.w, w1.x, w1.y, w1.z, w1.w,
                                       w2.x, w2.y, w2.z, w2.w, w3.x, w3.y, w3.z, w3.w};
#pragma unroll
                        for (int dx = 0; dx < 9; dx++)
#pragma unroll
                            for (int i = 0; i < 8; i++)
                                accb[j][i] = fmaf(rr[dx][i], w[i + dx], accb[j][i]);
                    }
                }
            }
            __syncthreads();   // FS free; fg/anum phase

            float regl = 0.f;
            if (consB) {
                float g[2][8];
#pragma unroll
                for (int j = 0; j < 2; j++) {
                    const int c = cB + 128 * j;
                    const float* fb = S + L_FLT + c * 36 + octB * 8;
                    float4 f0 = ld4(fb), f1 = ld4(fb + 4);
                    float fv[8] = {f0.x, f0.y, f0.z, f0.w, f1.x, f1.y, f1.z, f1.w};
#pragma unroll
                    for (int i = 0; i < 8; i++) {
                        g[j][i] = accb[j][i] + rw * fv[i];
                        regl = fmaf(fv[i], fv[i], regl);
                    }
                    st4(S + L_FG + c * 36 + octB * 8,
                        make_float4(g[j][0], g[j][1], g[j][2], g[j][3]));
                    st4(S + L_FG + c * 36 + octB * 8 + 4,
                        make_float4(g[j][4], g[j][5], g[j][6], g[j][7]));
                }
                float pp[8];
#pragma unroll
                for (int i = 0; i < 8; i++) pp[i] = g[0][i] * g[0][i] + g[1][i] * g[1][i];
                st4(S + L_FS + cB * 36 + octB * 8,     make_float4(pp[0], pp[1], pp[2], pp[3]));
                st4(S + L_FS + cB * 36 + octB * 8 + 4, make_float4(pp[4], pp[5], pp[6], pp[7]));
            }
#pragma unroll
            for (int off = 32; off > 0; off >>= 1) regl += __shfl_down(regl, off, 64);
            if ((tid & 63) == 0) atomicAdd(cst_g + 3 + it, regl);
            __syncthreads();
            if (tid < 32) {
                float s = 0.f;
                for (int c2 = 0; c2 < 128; c2++) s += S[L_FS + c2 * 36 + tid];
                S[L_ANUM + tid] = s;
            }
            __syncthreads();
        }

        // ---------- pass C: sg = corr(fg)*sw*mask; alpha; flt update ----------
        corr_pass(S, feat, L_FG, b, y, tid, lg, oct, dyA, compA);

        if (tid < 324) {
            const int kk = tid >> 2, o8 = (tid & 3) * 8;
            const int base = kk * 36 + o8;
            const float sw = S[L_CL + 162 + kk];
#pragma unroll
            for (int h = 0; h < 2; h++) {
                float4 s0 = ld4(S + L_FS + base + h * 4);
                float4 s1 = ld4(S + L_FS + 2916 + base + h * 4);
                float4 s2 = ld4(S + L_FS + 5832 + base + h * 4);
                float4 s3 = ld4(S + L_FS + 8748 + base + h * 4);
                float4 mk = ld4(S + L_SMASK + base + h * 4);
                float sg0 = sw * mk.x * (s0.x + s1.x + s2.x + s3.x);
                float sg1 = sw * mk.y * (s0.y + s1.y + s2.y + s3.y);
                float sg2 = sw * mk.z * (s0.z + s1.z + s2.z + s3.z);
                float sg3 = sw * mk.w * (s0.w + s1.w + s2.w + s3.w);
                st4(S + L_MRES + base + h * 4,   // mres dead -> sg^2 scratch
                    make_float4(sg0 * sg0, sg1 * sg1, sg2 * sg2, sg3 * sg3));
            }
        }
        __syncthreads();
        if (tid < 32) {
            float den = 0.f;
            for (int k = 0; k < 81; k++) den += S[L_MRES + k * 36 + tid];
            float num = S[L_ANUM + tid];
            float dd = fmaxf(den + rw * num, 1e-8f);
            S[L_ALPHA + tid] = step * num / dd;
        }
        __syncthreads();
        for (int i = tid; i < 2048; i += 1024) {
            int c = i >> 3, q = i & 7;
            float* fp = S + L_FLT + c * 36 + q * 4;
            float4 fl = ld4(fp);
            float4 g = ld4(S + L_FG + c * 36 + q * 4);
            float4 al = ld4(S + L_ALPHA + q * 4);
            fl.x -= al.x * g.x;
            fl.y -= al.y * g.y;
            fl.z -= al.z * g.z;
            fl.w -= al.w * g.w;
            st4(fp, fl);
        }
        __syncthreads();
    }

    // final: write flt row to output
    for (int i = tid; i < 2048; i += 1024) {
        int c = i >> 3, q = i & 7;
        st4(out + ((size_t)(b * NC + c) * NH + y) * NW + q * 4,
            ld4(S + L_FLT + c * 36 + q * 4));
    }
}

// ---------------- tail: write tr, tr_src, tr_reg (separate dispatch, no fences in mega) ----------------
__global__ void k_tail(const float* __restrict__ cst, const float* __restrict__ fr,
                       float* __restrict__ out) {
    int i = threadIdx.x;
    if (i < 3) {
        float rw = fmaxf(fr[0] * fr[0], 1e-10f) * (1.f / 65536.f);
        float src = 0.5f * cst[i] / 16.f;
        float reg = 0.5f * rw * cst[3 + i] / 16.f;
        out[4194304 + i] = src + reg;
        out[4194307 + i] = src;
        out[4194310 + i] = reg;
    }
}

extern "C" void kernel_launch(void* const* d_in, const int* in_sizes, int n_in,
                              void* d_out, int out_size, void* d_ws, size_t ws_size,
                              hipStream_t stream) {
    (void)in_sizes; (void)n_in; (void)out_size; (void)ws_size;
    const float* flt_in = (const float*)d_in[0];
    const float* feat   = (const float*)d_in[1];
    const float* lw     = (const float*)d_in[2];
    const float* mw     = (const float*)d_in[3];
    const float* sww    = (const float*)d_in[4];
    const float* lsl    = (const float*)d_in[5];
    const float* fr     = (const float*)d_in[6];
    float* out = (float*)d_out;
    float* cst = (float*)d_ws;

    hipMemsetAsync(cst, 0, 32, stream);   // src[3], reg[3]
    mega<<<512, 1024, 0, stream>>>(flt_in, feat, out, cst, lw, mw, sww, lsl, fr);
    k_tail<<<1, 64, 0, stream>>>(cst, fr, out);
}

// Round 8
// 595.857 us; speedup vs baseline: 1.9409x; 1.8616x over previous
//
#include <hip/hip_runtime.h>
#include <cstddef>

// ---------------- problem constants ----------------
#define NB 16
#define NC 256
#define NH 32
#define NW 32
#define NK 81

// LDS float offsets (1 block/CU, 160,512 B). Stride-36 rows spread all 8 bank-groups.
#define L_FLT    0        // [256][36]  flt row
#define L_FG     9216     // [256][36]  filter-grad row
#define L_MRES   18432    // [81][36]   mapped residuals (C reuses as sg^2 scratch)
#define L_SMASK  21348    // [81][36]
#define L_RING   24264    // 3 x [16ch][9dy][36] = 15552; overlays: red 4x2916, B-stage [256][44], pp [128][36]
#define L_CL     39816    // local consts [245]
#define L_ANUM   40064    // [32]
#define L_ALPHA  40096    // [32]
#define L_TOTAL  40128

#define CHUNK_F  5184     // one ring buffer: 16*9*36
#define CH_G     16384    // global float stride of a 16-channel chunk (16*NH*NW)

__device__ __forceinline__ float4 ld4(const float* p) { return *reinterpret_cast<const float4*>(p); }
__device__ __forceinline__ void st4(float* p, float4 v) { *reinterpret_cast<float4*>(p) = v; }

__device__ __forceinline__ void map_by(int bi, int& b, int& y) {
    int xcd = bi & 7, slot = bi >> 3;
    b = xcd * 2 + (slot >> 5);
    y = slot & 31;
}

// Raw barrier: drain LDS ops (lgkmcnt) but NOT global loads (vmcnt) -> staging loads
// issued 2 chunks ahead stay in flight across the barrier (T3/T4 counted-vmcnt pattern).
// __syncthreads() would emit s_waitcnt vmcnt(0) and destroy the pipeline depth.
__device__ __forceinline__ void bar_sync() {
    asm volatile("s_waitcnt lgkmcnt(0)" ::: "memory");
    __builtin_amdgcn_s_barrier();
    __builtin_amdgcn_sched_barrier(0);
}

// Correlation pass: scores(k,x) = sum_c A[c,x]*featpad[c,y+dy,x+dx-4]
// 16-ch chunks, ring-3 LDS, 1 raw barrier/chunk, depth-2 register prefetch.
// Group lg computes channels {lg*2, lg*2+1} of every other chunk -> per-accumulator
// FMA order is bitwise-identical to the r0/r2 kernel (8x32ch chunks, j=0,1).
__device__ __forceinline__ void corr_pass(float* S, const float* __restrict__ feat,
                                          int a_off, int b, int y, int tid,
                                          int lg, int oct, int dyA, bool vry) {
    float* ring = S + L_RING;
    // staging map: 1152 float4/chunk over 576 threads -> 2 each
    const int L0 = tid, L1 = tid + 576;
    const int c0 = L0 / 72, r0 = L0 - c0 * 72, d0 = r0 >> 3, q0 = r0 & 7;
    const int c1 = L1 / 72, r1 = L1 - c1 * 72, d1 = r1 >> 3, q1 = r1 & 7;
    const int ry0 = y + d0 - 4, ry1 = y + d1 - 4;
    const bool v0 = (ry0 >= 0) && (ry0 < 32);
    const bool v1 = (ry1 >= 0) && (ry1 < 32);
    const float* g0 = feat + ((size_t)(b * NC + c0) * NH + (v0 ? ry0 : 0)) * NW + q0 * 4;
    const float* g1 = feat + ((size_t)(b * NC + c1) * NH + (v1 ? ry1 : 0)) * NW + q1 * 4;
    const int s0 = c0 * 324 + d0 * 36 + q0 * 4;
    const int s1 = c1 * 324 + d1 * 36 + q1 * 4;

    float acc[9][8];
#pragma unroll
    for (int dx = 0; dx < 9; dx++)
#pragma unroll
        for (int i = 0; i < 8; i++) acc[dx][i] = 0.f;

    float4 RA0, RA1, RB0, RB1;
    // prologue: chunk0 -> B0; issue chunk1 (RA) + chunk2 (RB)
    if (v0) { RA0 = ld4(g0); }
    if (v1) { RA1 = ld4(g1); }
    if (v0) st4(ring + s0, RA0);
    if (v1) st4(ring + s1, RA1);
    if (v0) RA0 = ld4(g0 + CH_G);
    if (v1) RA1 = ld4(g1 + CH_G);
    if (v0) RB0 = ld4(g0 + 2 * CH_G);
    if (v1) RB1 = ld4(g1 + 2 * CH_G);
    bar_sync();   // B0 visible

#define CORR_COMPUTE(KK, BR)                                                        \
    if ((((KK) & 1) == (lg >> 3)) && vry) {                                         \
        const float* rowb = ring + (BR) * CHUNK_F + dyA * 36 + oct * 8;             \
        _Pragma("unroll")                                                           \
        for (int j = 0; j < 2; j++) {                                               \
            const int cl = (lg & 7) * 2 + j;                                        \
            const float* wb = rowb + cl * 324;                                      \
            float4 w0v = make_float4(0.f, 0.f, 0.f, 0.f);                           \
            float4 w3v = make_float4(0.f, 0.f, 0.f, 0.f);                           \
            if (oct > 0) w0v = ld4(wb - 4);                                         \
            float4 w1v = ld4(wb), w2v = ld4(wb + 4);                                \
            if (oct < 3) w3v = ld4(wb + 8);                                         \
            float w[16] = {w0v.x, w0v.y, w0v.z, w0v.w, w1v.x, w1v.y, w1v.z, w1v.w,  \
                           w2v.x, w2v.y, w2v.z, w2v.w, w3v.x, w3v.y, w3v.z, w3v.w}; \
            const float* fb = S + a_off + ((KK) * 16 + cl) * 36 + oct * 8;          \
            float4 f0 = ld4(fb), f1 = ld4(fb + 4);                                  \
            float f[8] = {f0.x, f0.y, f0.z, f0.w, f1.x, f1.y, f1.z, f1.w};          \
            _Pragma("unroll")                                                       \
            for (int dx = 0; dx < 9; dx++)                                          \
                _Pragma("unroll")                                                   \
                for (int i = 0; i < 8; i++)                                         \
                    acc[dx][i] = fmaf(f[i], w[i + dx], acc[dx][i]);                 \
        }                                                                           \
    }

    int bw = 1, br = 0;
#pragma unroll 1
    for (int k = 0; k < 16; k += 2) {
        // even k: RA holds chunk k+1; write it, issue chunk k+3 into RA
        if (v0) st4(ring + bw * CHUNK_F + s0, RA0);
        if (v1) st4(ring + bw * CHUNK_F + s1, RA1);
        if (k + 3 < 16) {
            if (v0) RA0 = ld4(g0 + (k + 3) * CH_G);
            if (v1) RA1 = ld4(g1 + (k + 3) * CH_G);
        }
        bar_sync();
        CORR_COMPUTE(k, br)
        bw = (bw == 2) ? 0 : bw + 1;
        br = (br == 2) ? 0 : br + 1;
        // odd k+1: RB holds chunk k+2; write it, issue chunk k+4 into RB
        if (k + 2 < 16) {
            if (v0) st4(ring + bw * CHUNK_F + s0, RB0);
            if (v1) st4(ring + bw * CHUNK_F + s1, RB1);
            if (k + 4 < 16) {
                if (v0) RB0 = ld4(g0 + (k + 4) * CH_G);
                if (v1) RB1 = ld4(g1 + (k + 4) * CH_G);
            }
        }
        bar_sync();
        CORR_COMPUTE(k + 1, br)
        bw = (bw == 2) ? 0 : bw + 1;
        br = (br == 2) ? 0 : br + 1;
    }
#undef CORR_COMPUTE
    __syncthreads();   // all computes done; ring free for reduce buffers

    // 4-buffer, 4-phase cross-group reduce (stride-36 rows; exact r2 order)
#pragma unroll 1
    for (int p = 0; p < 4; p++) {
        if ((lg >> 2) == p) {
            float* Bf = ring + (lg & 3) * 2916;
#pragma unroll
            for (int dx = 0; dx < 9; dx++) {
                int idx = (dyA * 9 + dx) * 36 + oct * 8;
                if (p == 0) {
                    st4(Bf + idx,     make_float4(acc[dx][0], acc[dx][1], acc[dx][2], acc[dx][3]));
                    st4(Bf + idx + 4, make_float4(acc[dx][4], acc[dx][5], acc[dx][6], acc[dx][7]));
                } else {
                    float4 t0 = ld4(Bf + idx), t1 = ld4(Bf + idx + 4);
                    t0.x += acc[dx][0]; t0.y += acc[dx][1]; t0.z += acc[dx][2]; t0.w += acc[dx][3];
                    t1.x += acc[dx][4]; t1.y += acc[dx][5]; t1.z += acc[dx][6]; t1.w += acc[dx][7];
                    st4(Bf + idx, t0); st4(Bf + idx + 4, t1);
                }
            }
        }
        __syncthreads();
    }
}

// ---------------- mega kernel: one block = one (b,y) row, all 3 iterations ----------------
__global__ __launch_bounds__(576, 2) void mega(const float* __restrict__ flt_in,
                                               const float* __restrict__ feat,
                                               float* __restrict__ out,
                                               float* __restrict__ cst_g,
                                               const float* __restrict__ lw,
                                               const float* __restrict__ mw,
                                               const float* __restrict__ sww,
                                               const float* __restrict__ lsl,
                                               const float* __restrict__ fr) {
    __shared__ float S[L_TOTAL];
    int b, y; map_by(blockIdx.x, b, y);
    const int tid = threadIdx.x;

    // A/C compute mapping (exact r2)
    const int lg  = tid / 36;
    const int r36 = tid - lg * 36;
    const int oct = r36 & 3;
    const int dyA = r36 >> 2;
    const int ryA = y + dyA - 4;
    const bool vry = (ryA >= 0 && ryA < 32);
    // B mapping (exact r2)
    const int octB = tid >> 7;
    const int cB   = tid & 127;
    const bool actB = (tid < 512);
    const int qB   = tid & 7;
    const int cB0  = tid >> 3;

    // local constants (k_const folded in)
    if (tid < 81) {
        int dyc = tid / 9, dxc = tid - dyc * 9;
        float dist = sqrtf((float)((dyc - 4) * (dyc - 4) + (dxc - 4) * (dxc - 4)));
        float lab = 0.f, mm = 0.f, ss = 0.f;
        for (int d = 0; d < 10; d++) {
            float diff = dist * 2.f - (float)d;
            float bv = (d < 9) ? fmaxf(0.f, 1.f - fabsf(diff))
                               : fminf(fmaxf(1.f + diff, 0.f), 1.f);
            lab += bv * lw[d];
            mm  += bv * mw[d];
            ss  += bv * sww[d];
        }
        S[L_CL + tid]       = lab;
        S[L_CL + 81 + tid]  = 1.f / (1.f + expf(-mm));
        S[L_CL + 162 + tid] = ss;
    } else if (tid == 81) {
        S[L_CL + 243] = expf(lsl[0]);
    } else if (tid == 82) {
        S[L_CL + 244] = fmaxf(fr[0] * fr[0], 1e-10f) * (1.f / 65536.f);
    }
    // stage flt row
    {
        const float* base = flt_in + ((size_t)b * NC * NH + y) * NW;
        for (int i = tid; i < 2048; i += 576) {
            int c = i >> 3, q = i & 7;
            st4(S + L_FLT + c * 36 + q * 4, ld4(base + c * (NH * NW) + q * 4));
        }
    }
    __syncthreads();
    const float step = S[L_CL + 243];
    const float rw   = S[L_CL + 244];

#pragma unroll 1
    for (int it = 0; it < 3; it++) {
        // ---------- pass A ----------
        corr_pass(S, feat, L_FLT, b, y, tid, lg, oct, dyA, vry);

        float srcl = 0.f;
        if (tid < 324) {
            const int kk = tid >> 2, o8 = (tid & 3) * 8;
            const int base = kk * 36 + o8;
            const float lab = S[L_CL + kk], m = S[L_CL + 81 + kk], sw = S[L_CL + 162 + kk];
            const float am = 0.5f * (1.f - m), ap = 0.5f * (1.f + m);
#pragma unroll
            for (int h = 0; h < 2; h++) {
                float4 s0 = ld4(S + L_RING + base + h * 4);
                float4 s1 = ld4(S + L_RING + 2916 + base + h * 4);
                float4 s2 = ld4(S + L_RING + 5832 + base + h * 4);
                float4 s3 = ld4(S + L_RING + 8748 + base + h * 4);
                float sv[4] = {s0.x + s1.x + s2.x + s3.x, s0.y + s1.y + s2.y + s3.y,
                               s0.z + s1.z + s2.z + s3.z, s0.w + s1.w + s2.w + s3.w};
                float tr[4], tm[4];
#pragma unroll
                for (int xi = 0; xi < 4; xi++) {
                    float s = sv[xi];
                    float act = am * fabsf(s) + ap * s;
                    float sgn = (s > 0.f ? 1.f : 0.f) - (s < 0.f ? 1.f : 0.f);
                    float msk = am * sgn + ap;
                    float lres = sw * (act - lab);
                    srcl = fmaf(lres, lres, srcl);
                    tr[xi] = msk * sw * lres;
                    tm[xi] = msk;
                }
                st4(S + L_MRES + base + h * 4,  make_float4(tr[0], tr[1], tr[2], tr[3]));
                st4(S + L_SMASK + base + h * 4, make_float4(tm[0], tm[1], tm[2], tm[3]));
            }
        }
#pragma unroll
        for (int off = 32; off > 0; off >>= 1) srcl += __shfl_down(srcl, off, 64);
        if ((tid & 63) == 0) atomicAdd(cst_g + it, srcl);
        __syncthreads();   // mres/smask visible; ring free

        // ---------- pass B (r2 structure, __syncthreads) ----------
        {
            const float4 z4 = make_float4(0.f, 0.f, 0.f, 0.f);
            for (int i = tid; i < 512; i += 576) {
                int c = i >> 1, h = i & 1;
                st4(S + L_RING + c * 44 + (h ? 36 : 0), z4);
            }
            float accb[2][8];
#pragma unroll
            for (int j = 0; j < 2; j++)
#pragma unroll
                for (int i = 0; i < 8; i++) accb[j][i] = 0.f;

            const int dy0 = (y < 4) ? (4 - y) : 0;
            const int dyN = (y > 27) ? (36 - y) : 9;
            float4 RB[4];
            if (actB) {
                int ry0 = y + dy0 - 4;
#pragma unroll
                for (int e = 0; e < 4; e++)
                    RB[e] = ld4(feat + (((size_t)(b * NC + cB0 + 64 * e)) * NH + ry0) * NW + qB * 4);
            }
#pragma unroll 1
            for (int dy = dy0; dy < dyN; ++dy) {
                __syncthreads();
                if (actB) {
#pragma unroll
                    for (int e = 0; e < 4; e++)
                        st4(S + L_RING + (cB0 + 64 * e) * 44 + 4 + qB * 4, RB[e]);
                    if (dy + 1 < dyN) {
                        int ry = y + dy - 3;
#pragma unroll
                        for (int e = 0; e < 4; e++)
                            RB[e] = ld4(feat + (((size_t)(b * NC + cB0 + 64 * e)) * NH + ry) * NW + qB * 4);
                    }
                }
                __syncthreads();
                if (actB) {
                    float rr[9][8];
#pragma unroll
                    for (int dx = 0; dx < 9; dx++) {
                        int mi = (dy * 9 + dx) * 36 + octB * 8;
                        float4 t0 = ld4(S + L_MRES + mi), t1 = ld4(S + L_MRES + mi + 4);
                        rr[dx][0] = t0.x; rr[dx][1] = t0.y; rr[dx][2] = t0.z; rr[dx][3] = t0.w;
                        rr[dx][4] = t1.x; rr[dx][5] = t1.y; rr[dx][6] = t1.z; rr[dx][7] = t1.w;
                    }
#pragma unroll
                    for (int j = 0; j < 2; j++) {
                        const int c = cB + 128 * j;
                        const float* wb = S + L_RING + c * 44 + octB * 8;
                        float4 w0 = ld4(wb), w1 = ld4(wb + 4), w2 = ld4(wb + 8), w3 = ld4(wb + 12);
                        float w[16] = {w0.x, w0.y, w0.z, w0.w, w1.x, w1.y, w1.z, w1.w,
                                       w2.x, w2.y, w2.z, w2.w, w3.x, w3.y, w3.z, w3.w};
#pragma unroll
                        for (int dx = 0; dx < 9; dx++)
#pragma unroll
                            for (int i = 0; i < 8; i++)
                                accb[j][i] = fmaf(rr[dx][i], w[i + dx], accb[j][i]);
                    }
                }
            }
            __syncthreads();

            float regl = 0.f;
            if (actB) {
                float g[2][8];
#pragma unroll
                for (int j = 0; j < 2; j++) {
                    const int c = cB + 128 * j;
                    const float* fb = S + L_FLT + c * 36 + octB * 8;
                    float4 f0 = ld4(fb), f1 = ld4(fb + 4);
                    float fv[8] = {f0.x, f0.y, f0.z, f0.w, f1.x, f1.y, f1.z, f1.w};
#pragma unroll
                    for (int i = 0; i < 8; i++) {
                        g[j][i] = accb[j][i] + rw * fv[i];
                        regl = fmaf(fv[i], fv[i], regl);
                    }
                    st4(S + L_FG + c * 36 + octB * 8,
                        make_float4(g[j][0], g[j][1], g[j][2], g[j][3]));
                    st4(S + L_FG + c * 36 + octB * 8 + 4,
                        make_float4(g[j][4], g[j][5], g[j][6], g[j][7]));
                }
                float pp[8];
#pragma unroll
                for (int i = 0; i < 8; i++) pp[i] = g[0][i] * g[0][i] + g[1][i] * g[1][i];
                st4(S + L_RING + cB * 36 + octB * 8,     make_float4(pp[0], pp[1], pp[2], pp[3]));
                st4(S + L_RING + cB * 36 + octB * 8 + 4, make_float4(pp[4], pp[5], pp[6], pp[7]));
            }
#pragma unroll
            for (int off = 32; off > 0; off >>= 1) regl += __shfl_down(regl, off, 64);
            if ((tid & 63) == 0) atomicAdd(cst_g + 3 + it, regl);
            __syncthreads();
            if (tid < 32) {
                float s = 0.f;
                for (int c2 = 0; c2 < 128; c2++) s += S[L_RING + c2 * 36 + tid];
                S[L_ANUM + tid] = s;
            }
            __syncthreads();
        }

        // ---------- pass C ----------
        corr_pass(S, feat, L_FG, b, y, tid, lg, oct, dyA, vry);

        if (tid < 324) {
            const int kk = tid >> 2, o8 = (tid & 3) * 8;
            const int base = kk * 36 + o8;
            const float sw = S[L_CL + 162 + kk];
#pragma unroll
            for (int h = 0; h < 2; h++) {
                float4 s0 = ld4(S + L_RING + base + h * 4);
                float4 s1 = ld4(S + L_RING + 2916 + base + h * 4);
                float4 s2 = ld4(S + L_RING + 5832 + base + h * 4);
                float4 s3 = ld4(S + L_RING + 8748 + base + h * 4);
                float4 mk = ld4(S + L_SMASK + base + h * 4);
                float sg0 = sw * mk.x * (s0.x + s1.x + s2.x + s3.x);
                float sg1 = sw * mk.y * (s0.y + s1.y + s2.y + s3.y);
                float sg2 = sw * mk.z * (s0.z + s1.z + s2.z + s3.z);
                float sg3 = sw * mk.w * (s0.w + s1.w + s2.w + s3.w);
                st4(S + L_MRES + base + h * 4,
                    make_float4(sg0 * sg0, sg1 * sg1, sg2 * sg2, sg3 * sg3));
            }
        }
        __syncthreads();
        if (tid < 32) {
            float den = 0.f;
            for (int k = 0; k < 81; k++) den += S[L_MRES + k * 36 + tid];
            float num = S[L_ANUM + tid];
            float dd = fmaxf(den + rw * num, 1e-8f);
            S[L_ALPHA + tid] = step * num / dd;
        }
        __syncthreads();
        for (int i = tid; i < 2048; i += 576) {
            int c = i >> 3, q = i & 7;
            float* fp = S + L_FLT + c * 36 + q * 4;
            float4 fl = ld4(fp);
            float4 g = ld4(S + L_FG + c * 36 + q * 4);
            float4 al = ld4(S + L_ALPHA + q * 4);
            fl.x -= al.x * g.x;
            fl.y -= al.y * g.y;
            fl.z -= al.z * g.z;
            fl.w -= al.w * g.w;
            st4(fp, fl);
        }
        __syncthreads();
    }

    // final: write flt row to output
    for (int i = tid; i < 2048; i += 576) {
        int c = i >> 3, q = i & 7;
        st4(out + ((size_t)(b * NC + c) * NH + y) * NW + q * 4,
            ld4(S + L_FLT + c * 36 + q * 4));
    }
}

// ---------------- tail: write tr, tr_src, tr_reg ----------------
__global__ void k_tail(const float* __restrict__ cst, const float* __restrict__ fr,
                       float* __restrict__ out) {
    int i = threadIdx.x;
    if (i < 3) {
        float rw = fmaxf(fr[0] * fr[0], 1e-10f) * (1.f / 65536.f);
        float src = 0.5f * cst[i] / 16.f;
        float reg = 0.5f * rw * cst[3 + i] / 16.f;
        out[4194304 + i] = src + reg;
        out[4194307 + i] = src;
        out[4194310 + i] = reg;
    }
}

extern "C" void kernel_launch(void* const* d_in, const int* in_sizes, int n_in,
                              void* d_out, int out_size, void* d_ws, size_t ws_size,
                              hipStream_t stream) {
    (void)in_sizes; (void)n_in; (void)out_size; (void)ws_size;
    const float* flt_in = (const float*)d_in[0];
    const float* feat   = (const float*)d_in[1];
    const float* lw     = (const float*)d_in[2];
    const float* mw     = (const float*)d_in[3];
    const float* sww    = (const float*)d_in[4];
    const float* lsl    = (const float*)d_in[5];
    const float* fr     = (const float*)d_in[6];
    float* out = (float*)d_out;
    float* cst = (float*)d_ws;

    hipMemsetAsync(cst, 0, 32, stream);   // src[3], reg[3]
    mega<<<512, 576, 0, stream>>>(flt_in, feat, out, cst, lw, mw, sww, lsl, fr);
    k_tail<<<1, 64, 0, stream>>>(cst, fr, out);
}

// Round 9
// 517.546 us; speedup vs baseline: 2.2346x; 1.1513x over previous
//
#include <hip/hip_runtime.h>
#include <cstddef>

// ---------------- problem constants ----------------
#define NB 16
#define NC 256
#define NH 32
#define NW 32
#define NK 81

// LDS float offsets (total 37,248 floats = 148,992 B, 1 block/CU)
#define L_FLT    0        // [256][36]  flt row
#define L_FG     9216     // [256][36]  filter-grad row
#define L_MRES   18432    // [81][36]   mapped residuals (C reuses as sg^2 scratch)
#define L_SMASK  21348    // [81][36]
#define L_FS     24264    // A/C: [32ch][9dy][44]=12672; red: 4x2916; B: [256][44]=11264; part: [128][36]
#define L_CL     36936    // local consts [245]
#define L_ANUM   37184    // [32]
#define L_ALPHA  37216    // [32]
#define L_TOTAL  37248

__device__ __forceinline__ float4 ld4(const float* p) { return *reinterpret_cast<const float4*>(p); }
__device__ __forceinline__ void st4(float* p, float4 v) { *reinterpret_cast<float4*>(p) = v; }

__device__ __forceinline__ void map_by(int bi, int& b, int& y) {
    int xcd = bi & 7, slot = bi >> 3;
    b = xcd * 2 + (slot >> 5);
    y = slot & 31;
}

// lgkm-only barrier: drains LDS ops (ds_write visibility / ds_read completion) but
// NOT global loads. __syncthreads() emits s_waitcnt vmcnt(0) before s_barrier, which
// drains the register prefetch of chunk k+1 right after issue -> full load latency
// exposed every chunk. With this barrier the compiler's dependency-counted vmcnt(N)
// before the next LDS store waits only for the loads it consumes (T3/T4 pattern).
__device__ __forceinline__ void bar_sync() {
    asm volatile("s_waitcnt lgkmcnt(0)" ::: "memory");
    __builtin_amdgcn_s_barrier();
    __builtin_amdgcn_sched_barrier(0);
}

// Correlation pass: scores(k,x) = sum_c A[c,x]*featpad[c,y+dy,x+dx-4]
// EXACT r2 layout/compute/order (bitwise-identical results); only the two chunk-loop
// barriers are lgkm-only so the chunk k+1 prefetch stays in flight across them.
__device__ __forceinline__ void corr_pass(float* S, const float* __restrict__ feat,
                                          int a_off, int b, int y, int tid,
                                          int lg, int oct, int dyA,
                                          int qs, int c0s, int dys, bool vst, int rys) {
    float* fs = S + L_FS;
    // prefetch chunk-0 global loads before the zero phase (hide latency)
    const float* gbase = feat + (((size_t)b * NC) * NH + rys) * NW + qs * 4;
    float4 R[4];
    if (vst) {
#pragma unroll
        for (int k2 = 0; k2 < 4; k2++)
            R[k2] = ld4(gbase + (size_t)(c0s + 8 * k2) * (NH * NW));
    }
    const float4 z4 = make_float4(0.f, 0.f, 0.f, 0.f);
    // zero only halo quads (floats 0..3 and 36..39 of each of the 288 [44] rows)
    {
        int row = tid >> 1;
        st4(fs + row * 44 + ((tid & 1) ? 36 : 0), z4);
    }
    // zero full rows of out-of-range dy (only near y edges)
    if (y < 4 || y > 27) {
        for (int dyv = 0; dyv < 9; ++dyv) {
            int ryv = y + dyv - 4;
            if (ryv < 0 || ryv >= 32) {
                for (int i = tid; i < 320; i += 576) {
                    int c = i / 10, q = i - c * 10;
                    st4(fs + c * 396 + dyv * 44 + q * 4, z4);
                }
            }
        }
    }
    bar_sync();

    float acc[9][8];
#pragma unroll
    for (int dx = 0; dx < 9; dx++)
#pragma unroll
        for (int i = 0; i < 8; i++) acc[dx][i] = 0.f;

#pragma unroll 1
    for (int chunk = 0; chunk < 8; chunk++) {
        if (vst) {
#pragma unroll
            for (int k2 = 0; k2 < 4; k2++)
                st4(fs + (c0s + 8 * k2) * 396 + dys * 44 + 4 + qs * 4, R[k2]);
        }
        bar_sync();               // staging visible (lgkm); k+1 loads may stay in flight
        if (chunk < 7 && vst) {
#pragma unroll
            for (int k2 = 0; k2 < 4; k2++)
                R[k2] = ld4(gbase + (size_t)((chunk + 1) * 32 + c0s + 8 * k2) * (NH * NW));
        }
#pragma unroll
        for (int j = 0; j < 2; j++) {
            const int cl = lg * 2 + j;
            const float* wb = fs + cl * 396 + dyA * 44 + oct * 8;
            float4 w0 = ld4(wb), w1 = ld4(wb + 4), w2 = ld4(wb + 8), w3 = ld4(wb + 12);
            float w[16] = {w0.x, w0.y, w0.z, w0.w, w1.x, w1.y, w1.z, w1.w,
                           w2.x, w2.y, w2.z, w2.w, w3.x, w3.y, w3.z, w3.w};
            const float* fb = S + a_off + (chunk * 32 + cl) * 36 + oct * 8;
            float4 f0 = ld4(fb), f1 = ld4(fb + 4);
            float f[8] = {f0.x, f0.y, f0.z, f0.w, f1.x, f1.y, f1.z, f1.w};
#pragma unroll
            for (int dx = 0; dx < 9; dx++)
#pragma unroll
                for (int i = 0; i < 8; i++)
                    acc[dx][i] = fmaf(f[i], w[i + dx], acc[dx][i]);
        }
        bar_sync();               // reads done (lgkm); prefetch loads still in flight
    }
    // 4-buffer, 4-phase cross-group reduce (stride-36 rows: conflict-free)
#pragma unroll 1
    for (int p = 0; p < 4; p++) {
        if ((lg >> 2) == p) {
            float* Bf = fs + (lg & 3) * 2916;
#pragma unroll
            for (int dx = 0; dx < 9; dx++) {
                int idx = (dyA * 9 + dx) * 36 + oct * 8;
                if (p == 0) {
                    st4(Bf + idx,     make_float4(acc[dx][0], acc[dx][1], acc[dx][2], acc[dx][3]));
                    st4(Bf + idx + 4, make_float4(acc[dx][4], acc[dx][5], acc[dx][6], acc[dx][7]));
                } else {
                    float4 t0 = ld4(Bf + idx), t1 = ld4(Bf + idx + 4);
                    t0.x += acc[dx][0]; t0.y += acc[dx][1]; t0.z += acc[dx][2]; t0.w += acc[dx][3];
                    t1.x += acc[dx][4]; t1.y += acc[dx][5]; t1.z += acc[dx][6]; t1.w += acc[dx][7];
                    st4(Bf + idx, t0); st4(Bf + idx + 4, t1);
                }
            }
        }
        __syncthreads();
    }
}

// ---------------- mega kernel: one block = one (b,y) row, all 3 iterations ----------------
__global__ __launch_bounds__(576, 2) void mega(const float* __restrict__ flt_in,
                                               const float* __restrict__ feat,
                                               float* __restrict__ out,
                                               float* __restrict__ cst_g,
                                               const float* __restrict__ lw,
                                               const float* __restrict__ mw,
                                               const float* __restrict__ sww,
                                               const float* __restrict__ lsl,
                                               const float* __restrict__ fr) {
    __shared__ float S[L_TOTAL];
    int b, y; map_by(blockIdx.x, b, y);
    const int tid = threadIdx.x;

    // A/C compute mapping
    const int lg  = tid / 36;
    const int r36 = tid - lg * 36;
    const int oct = r36 & 3;
    const int dyA = r36 >> 2;
    // staging mapping (A/C chunks)
    const int qs  = tid & 7;
    const int rs  = tid >> 3;
    const int c0s = rs / 9;
    const int dys = rs - c0s * 9;
    const int rys = y + dys - 4;
    const bool vst = (rys >= 0 && rys < 32);
    // B mapping: lanes read CONSECUTIVE channels -> conflict-free LDS access
    const int octB = tid >> 7;          // 0..3 for active threads
    const int cB   = tid & 127;
    const bool actB = (tid < 512);
    const int qB   = tid & 7;           // B staging
    const int cB0  = tid >> 3;

    // local constants (k_const folded in; per-block LDS-local)
    if (tid < 81) {
        int dyc = tid / 9, dxc = tid - dyc * 9;
        float dist = sqrtf((float)((dyc - 4) * (dyc - 4) + (dxc - 4) * (dxc - 4)));
        float lab = 0.f, mm = 0.f, ss = 0.f;
        for (int d = 0; d < 10; d++) {
            float diff = dist * 2.f - (float)d;
            float bv = (d < 9) ? fmaxf(0.f, 1.f - fabsf(diff))
                               : fminf(fmaxf(1.f + diff, 0.f), 1.f);
            lab += bv * lw[d];
            mm  += bv * mw[d];
            ss  += bv * sww[d];
        }
        S[L_CL + tid]       = lab;
        S[L_CL + 81 + tid]  = 1.f / (1.f + expf(-mm));
        S[L_CL + 162 + tid] = ss;
    } else if (tid == 81) {
        S[L_CL + 243] = expf(lsl[0]);
    } else if (tid == 82) {
        S[L_CL + 244] = fmaxf(fr[0] * fr[0], 1e-10f) * (1.f / 65536.f);
    }
    // stage flt row
    {
        const float* base = flt_in + ((size_t)b * NC * NH + y) * NW;
        for (int i = tid; i < 2048; i += 576) {
            int c = i >> 3, q = i & 7;
            st4(S + L_FLT + c * 36 + q * 4, ld4(base + c * (NH * NW) + q * 4));
        }
    }
    __syncthreads();
    const float step = S[L_CL + 243];
    const float rw   = S[L_CL + 244];

#pragma unroll 1
    for (int it = 0; it < 3; it++) {
        // ---------- pass A: scores = corr(flt), elementwise -> mres/smask, src loss ----------
        corr_pass(S, feat, L_FLT, b, y, tid, lg, oct, dyA, qs, c0s, dys, vst, rys);

        float srcl = 0.f;
        if (tid < 324) {
            const int kk = tid >> 2, o8 = (tid & 3) * 8;
            const int base = kk * 36 + o8;
            const float lab = S[L_CL + kk], m = S[L_CL + 81 + kk], sw = S[L_CL + 162 + kk];
            const float am = 0.5f * (1.f - m), ap = 0.5f * (1.f + m);
#pragma unroll
            for (int h = 0; h < 2; h++) {
                float4 s0 = ld4(S + L_FS + base + h * 4);
                float4 s1 = ld4(S + L_FS + 2916 + base + h * 4);
                float4 s2 = ld4(S + L_FS + 5832 + base + h * 4);
                float4 s3 = ld4(S + L_FS + 8748 + base + h * 4);
                float sv[4] = {s0.x + s1.x + s2.x + s3.x, s0.y + s1.y + s2.y + s3.y,
                               s0.z + s1.z + s2.z + s3.z, s0.w + s1.w + s2.w + s3.w};
                float tr[4], tm[4];
#pragma unroll
                for (int xi = 0; xi < 4; xi++) {
                    float s = sv[xi];
                    float act = am * fabsf(s) + ap * s;
                    float sgn = (s > 0.f ? 1.f : 0.f) - (s < 0.f ? 1.f : 0.f);
                    float msk = am * sgn + ap;
                    float lres = sw * (act - lab);
                    srcl = fmaf(lres, lres, srcl);
                    tr[xi] = msk * sw * lres;
                    tm[xi] = msk;
                }
                st4(S + L_MRES + base + h * 4,  make_float4(tr[0], tr[1], tr[2], tr[3]));
                st4(S + L_SMASK + base + h * 4, make_float4(tm[0], tm[1], tm[2], tm[3]));
            }
        }
#pragma unroll
        for (int off = 32; off > 0; off >>= 1) srcl += __shfl_down(srcl, off, 64);
        if ((tid & 63) == 0) atomicAdd(cst_g + it, srcl);
        __syncthreads();   // mres/smask visible; red buffers free

        // ---------- pass B: fg = corr_T(mres) + rw*flt; alpha_num; reg loss ----------
        {
            const float4 z4 = make_float4(0.f, 0.f, 0.f, 0.f);
            // zero x-halos of B layout [256][44]: quads 0 and 9 of each row
            for (int i = tid; i < 512; i += 576) {
                int c = i >> 1, h = i & 1;
                st4(S + L_FS + c * 44 + (h ? 36 : 0), z4);
            }
            float accb[2][8];
#pragma unroll
            for (int j = 0; j < 2; j++)
#pragma unroll
                for (int i = 0; i < 8; i++) accb[j][i] = 0.f;

            const int dy0 = (y < 4) ? (4 - y) : 0;
            const int dyN = (y > 27) ? (36 - y) : 9;
            float4 R[4];
            if (actB) {
                int ry0 = y + dy0 - 4;
#pragma unroll
                for (int k = 0; k < 4; k++)
                    R[k] = ld4(feat + (((size_t)(b * NC + cB0 + 64 * k)) * NH + ry0) * NW + qB * 4);
            }
#pragma unroll 1
            for (int dy = dy0; dy < dyN; ++dy) {
                bar_sync();                       // prior reads of FS done (lgkm only)
                if (actB) {
#pragma unroll
                    for (int k = 0; k < 4; k++)
                        st4(S + L_FS + (cB0 + 64 * k) * 44 + 4 + qB * 4, R[k]);
                    if (dy + 1 < dyN) {           // prefetch next dy into regs
                        int ry = y + dy - 3;
#pragma unroll
                        for (int k = 0; k < 4; k++)
                            R[k] = ld4(feat + (((size_t)(b * NC + cB0 + 64 * k)) * NH + ry) * NW + qB * 4);
                    }
                }
                bar_sync();                       // staging visible; prefetch stays in flight
                if (actB) {
                    float rr[9][8];
#pragma unroll
                    for (int dx = 0; dx < 9; dx++) {
                        int mi = (dy * 9 + dx) * 36 + octB * 8;     // wave-uniform addr: broadcast
                        float4 t0 = ld4(S + L_MRES + mi), t1 = ld4(S + L_MRES + mi + 4);
                        rr[dx][0] = t0.x; rr[dx][1] = t0.y; rr[dx][2] = t0.z; rr[dx][3] = t0.w;
                        rr[dx][4] = t1.x; rr[dx][5] = t1.y; rr[dx][6] = t1.z; rr[dx][7] = t1.w;
                    }
#pragma unroll
                    for (int j = 0; j < 2; j++) {
                        const int c = cB + 128 * j;                 // consecutive c across lanes
                        const float* wb = S + L_FS + c * 44 + octB * 8;
                        float4 w0 = ld4(wb), w1 = ld4(wb + 4), w2 = ld4(wb + 8), w3 = ld4(wb + 12);
                        float w[16] = {w0.x, w0.y, w0.z, w0.w, w1.x, w1.y, w1.z, w1.w,
                                       w2.x, w2.y, w2.z, w2.w, w3.x, w3.y, w3.z, w3.w};
#pragma unroll
                        for (int dx = 0; dx < 9; dx++)
#pragma unroll
                            for (int i = 0; i < 8; i++)
                                accb[j][i] = fmaf(rr[dx][i], w[i + dx], accb[j][i]);
                    }
                }
            }
            __syncthreads();   // fs free; fg/anum phase

            float regl = 0.f;
            if (actB) {
                float g[2][8];
#pragma unroll
                for (int j = 0; j < 2; j++) {
                    const int c = cB + 128 * j;
                    const float* fb = S + L_FLT + c * 36 + octB * 8;
                    float4 f0 = ld4(fb), f1 = ld4(fb + 4);
                    float fv[8] = {f0.x, f0.y, f0.z, f0.w, f1.x, f1.y, f1.z, f1.w};
#pragma unroll
                    for (int i = 0; i < 8; i++) {
                        g[j][i] = accb[j][i] + rw * fv[i];
                        regl = fmaf(fv[i], fv[i], regl);
                    }
                    st4(S + L_FG + c * 36 + octB * 8,
                        make_float4(g[j][0], g[j][1], g[j][2], g[j][3]));
                    st4(S + L_FG + c * 36 + octB * 8 + 4,
                        make_float4(g[j][4], g[j][5], g[j][6], g[j][7]));
                }
                float pp[8];
#pragma unroll
                for (int i = 0; i < 8; i++) pp[i] = g[0][i] * g[0][i] + g[1][i] * g[1][i];
                st4(S + L_FS + cB * 36 + octB * 8,     make_float4(pp[0], pp[1], pp[2], pp[3]));
                st4(S + L_FS + cB * 36 + octB * 8 + 4, make_float4(pp[4], pp[5], pp[6], pp[7]));
            }
#pragma unroll
            for (int off = 32; off > 0; off >>= 1) regl += __shfl_down(regl, off, 64);
            if ((tid & 63) == 0) atomicAdd(cst_g + 3 + it, regl);
            __syncthreads();
            if (tid < 32) {
                float s = 0.f;
                for (int c2 = 0; c2 < 128; c2++) s += S[L_FS + c2 * 36 + tid];
                S[L_ANUM + tid] = s;
            }
            __syncthreads();
        }

        // ---------- pass C: sg = corr(fg)*sw*mask; alpha; flt update ----------
        corr_pass(S, feat, L_FG, b, y, tid, lg, oct, dyA, qs, c0s, dys, vst, rys);

        if (tid < 324) {
            const int kk = tid >> 2, o8 = (tid & 3) * 8;
            const int base = kk * 36 + o8;
            const float sw = S[L_CL + 162 + kk];
#pragma unroll
            for (int h = 0; h < 2; h++) {
                float4 s0 = ld4(S + L_FS + base + h * 4);
                float4 s1 = ld4(S + L_FS + 2916 + base + h * 4);
                float4 s2 = ld4(S + L_FS + 5832 + base + h * 4);
                float4 s3 = ld4(S + L_FS + 8748 + base + h * 4);
                float4 mk = ld4(S + L_SMASK + base + h * 4);
                float sg0 = sw * mk.x * (s0.x + s1.x + s2.x + s3.x);
                float sg1 = sw * mk.y * (s0.y + s1.y + s2.y + s3.y);
                float sg2 = sw * mk.z * (s0.z + s1.z + s2.z + s3.z);
                float sg3 = sw * mk.w * (s0.w + s1.w + s2.w + s3.w);
                st4(S + L_MRES + base + h * 4,   // mres dead -> sg^2 scratch
                    make_float4(sg0 * sg0, sg1 * sg1, sg2 * sg2, sg3 * sg3));
            }
        }
        __syncthreads();
        if (tid < 32) {
            float den = 0.f;
            for (int k = 0; k < 81; k++) den += S[L_MRES + k * 36 + tid];
            float num = S[L_ANUM + tid];
            float dd = fmaxf(den + rw * num, 1e-8f);
            S[L_ALPHA + tid] = step * num / dd;
        }
        __syncthreads();
        for (int i = tid; i < 2048; i += 576) {
            int c = i >> 3, q = i & 7;
            float* fp = S + L_FLT + c * 36 + q * 4;
            float4 fl = ld4(fp);
            float4 g = ld4(S + L_FG + c * 36 + q * 4);
            float4 al = ld4(S + L_ALPHA + q * 4);
            fl.x -= al.x * g.x;
            fl.y -= al.y * g.y;
            fl.z -= al.z * g.z;
            fl.w -= al.w * g.w;
            st4(fp, fl);
        }
        __syncthreads();
    }

    // final: write flt row to output
    for (int i = tid; i < 2048; i += 576) {
        int c = i >> 3, q = i & 7;
        st4(out + ((size_t)(b * NC + c) * NH + y) * NW + q * 4,
            ld4(S + L_FLT + c * 36 + q * 4));
    }
}

// ---------------- tail: write tr, tr_src, tr_reg (separate dispatch, no fences in mega) ----------------
__global__ void k_tail(const float* __restrict__ cst, const float* __restrict__ fr,
                       float* __restrict__ out) {
    int i = threadIdx.x;
    if (i < 3) {
        float rw = fmaxf(fr[0] * fr[0], 1e-10f) * (1.f / 65536.f);
        float src = 0.5f * cst[i] / 16.f;
        float reg = 0.5f * rw * cst[3 + i] / 16.f;
        out[4194304 + i] = src + reg;
        out[4194307 + i] = src;
        out[4194310 + i] = reg;
    }
}

extern "C" void kernel_launch(void* const* d_in, const int* in_sizes, int n_in,
                              void* d_out, int out_size, void* d_ws, size_t ws_size,
                              hipStream_t stream) {
    (void)in_sizes; (void)n_in; (void)out_size; (void)ws_size;
    const float* flt_in = (const float*)d_in[0];
    const float* feat   = (const float*)d_in[1];
    const float* lw     = (const float*)d_in[2];
    const float* mw     = (const float*)d_in[3];
    const float* sww    = (const float*)d_in[4];
    const float* lsl    = (const float*)d_in[5];
    const float* fr     = (const float*)d_in[6];
    float* out = (float*)d_out;
    float* cst = (float*)d_ws;

    hipMemsetAsync(cst, 0, 32, stream);   // src[3], reg[3]
    mega<<<512, 576, 0, stream>>>(flt_in, feat, out, cst, lw, mw, sww, lsl, fr);
    k_tail<<<1, 64, 0, stream>>>(cst, fr, out);
}